// Round 5
// baseline (341.236 us; speedup 1.0000x reference)
//
#include <hip/hip_runtime.h>
#include <hip/hip_bf16.h>
#include <stdint.h>

typedef __hip_bfloat16 bf16;
typedef __attribute__((ext_vector_type(4))) float f32x4;
typedef __attribute__((ext_vector_type(8))) short short8;
typedef __attribute__((ext_vector_type(4))) unsigned short u16x4;

#define SEQ   4096
#define CDIM  1024

// ---------------------------------------------------------------------------
// async global->LDS, 16B per lane. LDS dest = wave-uniform base + lane*16.
// ---------------------------------------------------------------------------
__device__ __forceinline__ void async_load16(const void* g, void* l) {
  auto gp = reinterpret_cast<const __attribute__((address_space(1))) uint32_t*>(
      reinterpret_cast<uintptr_t>(g));
  auto lp = reinterpret_cast<__attribute__((address_space(3))) uint32_t*>(
      static_cast<uint32_t>(reinterpret_cast<uintptr_t>(l)));
  __builtin_amdgcn_global_load_lds(gp, lp, 16, 0, 0);
}

// ---------------------------------------------------------------------------
// fused fp32 -> bf16 convert for x, w_qkv, w_proj (one launch). nt loads:
// sources are read-once; keep them out of L2/L3 (outputs re-read soon, cached).
// ---------------------------------------------------------------------------
__global__ __launch_bounds__(256) void convert3_kernel(const float* __restrict__ x,
                                                       const float* __restrict__ wq,
                                                       const float* __restrict__ wp,
                                                       bf16* __restrict__ xb,
                                                       bf16* __restrict__ wqb,
                                                       bf16* __restrict__ wpb) {
  int i = blockIdx.x * 256 + threadIdx.x;
  const float* src;
  bf16* dst;
  int off;
  if (i < 4194304)      { src = x;  dst = xb;  off = i; }
  else if (i < 4980736) { src = wq; dst = wqb; off = i - 4194304; }
  else                  { src = wp; dst = wpb; off = i - 4980736; }
  f32x4 f = __builtin_nontemporal_load(((const f32x4*)src) + off);
  union { bf16 b[4]; u16x4 u; } c;
  c.b[0] = __float2bfloat16(f[0]);
  c.b[1] = __float2bfloat16(f[1]);
  c.b[2] = __float2bfloat16(f[2]);
  c.b[3] = __float2bfloat16(f[3]);
  ((u16x4*)dst)[off] = c.u;
}

// ---------------------------------------------------------------------------
// 256x256 8-phase bf16 GEMM, TILE-CHAINED (persistent NTILES per block).
//   C[m][n] = sum_k A[m][k] * B[n][k]   (both row-major, K-contiguous)
// 512 threads = 8 waves (2M x 4N); per-wave output 128x64; BK=64.
// LDS: A0,B0,A1,B1 each [256][64] bf16 = 128 KiB (1 block/CU).
// T2: LDS[row][c] = global[row][c ^ ((row&7)*8)] via pre-swizzled global src
// + matching XOR on ds_read (8 lanes/bank-quad, conflict-free; verified 0).
// Chaining: block b handles tiles {b, b+256, b+512}. The K stream is
// continuous (0..1023 x3); at wrap iterations (kl==896) the +128/+192 stage
// calls use the NEXT tile's base with offsets 0/64 — region timing identical,
// so the vmcnt(6)-at-ph4/ph8 proof is unchanged. Epilogue + acc reset run
// between wrap iterations while the next tile's staging is in flight
// (fill/drain amortized: paid once per block instead of once per tile).
// ---------------------------------------------------------------------------
#define BARR()  __builtin_amdgcn_s_barrier()
#define LGKM0() asm volatile("s_waitcnt lgkmcnt(0)" ::: "memory")
#define VMW6()  asm volatile("s_waitcnt vmcnt(6)" ::: "memory")
#define VMW0()  asm volatile("s_waitcnt vmcnt(0)" ::: "memory")
#define SP(x)   __builtin_amdgcn_s_setprio(x)

// A half h: rows {h*64 + [0,64)} u {h*64+128 + [0,64)}; wave w stages 8 rows.
#define STA(buf, base, kc, h)                                                  \
  {                                                                            \
    const int ra_ = (h) * 64 + w * 8;                                          \
    async_load16((base) + (size_t)(ra_ + lr8) * K + (kc) + cs,                 \
                 (buf) + ra_ * 64);                                            \
    async_load16((base) + (size_t)(ra_ + 128 + lr8) * K + (kc) + cs,           \
                 (buf) + (ra_ + 128) * 64);                                    \
  }
// B half h: rows {wn'*64 + h*32 + [0,32) : wn'=0..3}; wave w stages 8 rows.
#define STB(buf, base, kc, h)                                                  \
  {                                                                            \
    const int rb_ = (w & 3) * 8 + (w >> 2) * 64 + (h) * 32;                    \
    async_load16((base) + (size_t)(rb_ + lr8) * K + (kc) + cs,                 \
                 (buf) + rb_ * 64);                                            \
    async_load16((base) + (size_t)(rb_ + 128 + lr8) * K + (kc) + cs,           \
                 (buf) + (rb_ + 128) * 64);                                    \
  }

#define RD_A(buf, h)                                                           \
  {                                                                            \
    _Pragma("unroll") for (int mi = 0; mi < 4; ++mi) {                         \
      const unsigned short* p_ = (buf) + (arow0 + (h) * 64 + mi * 16) * 64;    \
      af[mi][0] = *(const short8*)(p_ + ((lq * 8) ^ sw));                      \
      af[mi][1] = *(const short8*)(p_ + ((32 + lq * 8) ^ sw));                 \
    }                                                                          \
  }
#define RD_B(buf, h)                                                           \
  {                                                                            \
    _Pragma("unroll") for (int ni = 0; ni < 2; ++ni) {                         \
      const unsigned short* p_ = (buf) + (brow0 + (h) * 32 + ni * 16) * 64;    \
      bfr[h][ni][0] = *(const short8*)(p_ + ((lq * 8) ^ sw));                  \
      bfr[h][ni][1] = *(const short8*)(p_ + ((32 + lq * 8) ^ sw));             \
    }                                                                          \
  }

#define MMA(MQ, NQ)                                                            \
  {                                                                            \
    _Pragma("unroll") for (int ks = 0; ks < 2; ++ks)                           \
      _Pragma("unroll") for (int mi = 0; mi < 4; ++mi)                         \
        _Pragma("unroll") for (int ni = 0; ni < 2; ++ni)                       \
          acc[(MQ) * 4 + mi][(NQ) * 2 + ni] =                                  \
              __builtin_amdgcn_mfma_f32_16x16x32_bf16(                         \
                  af[mi][ks], bfr[NQ][ni][ks],                                 \
                  acc[(MQ) * 4 + mi][(NQ) * 2 + ni], 0, 0, 0);                 \
  }

// full iteration: compute buf0 [ph1-4], buf1 [ph5-8]; stage kl+64 B1h0 (cur),
// (k1 = kl+128 -> buf0) and (k2 = kl+192 -> buf1 parts) from sA/sB.
#define FULL_ITER_BODY()                                                       \
  RD_A(A0, 0); RD_B(B0, 0); STB(B1, BgC, kl + 64, 0);                          \
  BARR(); LGKM0(); SP(1); MMA(0, 0); SP(0); BARR();                            \
  RD_B(B0, 1); STA(A0, sA, k1, 0);                                             \
  BARR(); LGKM0(); SP(1); MMA(0, 1); SP(0); BARR();                            \
  RD_A(A0, 1); STB(B0, sB, k1, 1);                                             \
  BARR(); LGKM0(); SP(1); MMA(1, 1); SP(0); BARR();                            \
  STA(A0, sA, k1, 1); VMW6();                                                  \
  BARR(); SP(1); MMA(1, 0); SP(0); BARR();                                     \
  RD_A(A1, 0); RD_B(B1, 0); STB(B0, sB, k1, 0);                                \
  BARR(); LGKM0(); SP(1); MMA(0, 0); SP(0); BARR();                            \
  RD_B(B1, 1); STA(A1, sA, k2, 0);                                             \
  BARR(); LGKM0(); SP(1); MMA(0, 1); SP(0); BARR();                            \
  RD_A(A1, 1); STB(B1, sB, k2, 1);                                             \
  BARR(); LGKM0(); SP(1); MMA(1, 1); SP(0); BARR();                            \
  STA(A1, sA, k2, 1); VMW6();                                                  \
  BARR(); SP(1); MMA(1, 0); SP(0); BARR();

// last iteration of the last tile: only B1h0@960+64 never exists; stage B1h0
// for the current tile's second K-tile at ph1, then drain.
#define FINAL_ITER_BODY()                                                      \
  RD_A(A0, 0); RD_B(B0, 0); STB(B1, BgC, 960, 0);                              \
  BARR(); LGKM0(); SP(1); MMA(0, 0); SP(0); BARR();                            \
  RD_B(B0, 1);                                                                 \
  BARR(); LGKM0(); SP(1); MMA(0, 1); SP(0); BARR();                            \
  RD_A(A0, 1);                                                                 \
  BARR(); LGKM0(); SP(1); MMA(1, 1); SP(0); BARR();                            \
  VMW0();                                                                      \
  BARR(); SP(1); MMA(1, 0); SP(0); BARR();                                     \
  RD_A(A1, 0); RD_B(B1, 0);                                                    \
  BARR(); LGKM0(); SP(1); MMA(0, 0); SP(0); BARR();                            \
  RD_B(B1, 1);                                                                 \
  BARR(); LGKM0(); SP(1); MMA(0, 1); SP(0); BARR();                            \
  RD_A(A1, 1);                                                                 \
  BARR(); LGKM0(); SP(1); MMA(1, 1); SP(0); BARR();                            \
  SP(1); MMA(1, 0); SP(0);

template <int EPI, int NTILES, int GNX>
__global__ __launch_bounds__(512, 2) void gemm256(const bf16* __restrict__ X,
                                                  const bf16* __restrict__ W,
                                                  const float* __restrict__ bias,
                                                  bf16* __restrict__ Qo,
                                                  bf16* __restrict__ Ko,
                                                  bf16* __restrict__ Vo,
                                                  float* __restrict__ Out,
                                                  const int K) {
  __shared__ __attribute__((aligned(16))) unsigned short lds[4][256 * 64];
  unsigned short* const A0 = lds[0];
  unsigned short* const B0 = lds[1];
  unsigned short* const A1 = lds[2];
  unsigned short* const B1 = lds[3];

  const int tid  = threadIdx.x;
  const int w    = tid >> 6, lane = tid & 63;
  const int wm   = w >> 2,   wn   = w & 3;
  const int lr   = lane & 15, lq  = lane >> 4;

  const int sw   = (lr & 7) << 3;                          // read-side XOR (elems)
  const int cs   = (((lane & 7) ^ (lane >> 3)) << 3);      // src-side pre-swizzle
  const int lr8  = lane >> 3;

  const int arow0 = wm * 128 + lr;
  const int brow0 = wn * 64 + lr;

  // ---- tile chain state: current tile + next tile bases ----
  int id = (int)blockIdx.x;
  int bn = id % GNX, bm = id / GNX;
  bool swapped = (EPI == 0) && (bn < 4);
  const bf16* AgC;
  const bf16* BgC;
  const bf16* AgX;
  const bf16* BgX;
  {
    const bf16* Xg = X + (size_t)(bm * 256) * K;
    const bf16* Wg = W + (size_t)(bn * 256) * K;
    AgC = swapped ? Wg : Xg;
    BgC = swapped ? Xg : Wg;
    const int idX = id + 256;                 // may be OOB; only dereferenced
    const int bnX = idX % GNX, bmX = idX / GNX;  // when a next tile exists
    const bool swX = (EPI == 0) && (bnX < 4);
    const bf16* XgX = X + (size_t)(bmX * 256) * K;
    const bf16* WgX = W + (size_t)(bnX * 256) * K;
    AgX = swX ? WgX : XgX;
    BgX = swX ? XgX : WgX;
  }

  short8 af[4][2], bfr[2][2][2];   // bfr[half][ni][ks]
  f32x4 acc[8][4] = {};

  auto epilogue = [&](int bmv, int bnv, bool swv) {
    if constexpr (EPI == 0) {
      if (swv) {
        // Q block: m = channel j, col = token t. 4 regs = 4 consecutive d.
#pragma unroll
        for (int mt = 0; mt < 8; ++mt) {
          const int j0 = bnv * 256 + wm * 128 + mt * 16 + lq * 4;
          const int hh = j0 >> 6, d0 = j0 & 63;
#pragma unroll
          for (int nt = 0; nt < 4; ++nt) {
            const int t = bmv * 256 + wn * 64 + nt * 16 + lr;
            const int b = t >> 12, n = t & 4095;
            union { bf16 v[4]; u16x4 u; } pk;
#pragma unroll
            for (int r = 0; r < 4; ++r) {
              float v = acc[mt][nt][r];
              v = (v > 0.0f) ? (v + 1.0f) : __expf(v);
              pk.v[r] = __float2bfloat16(v);
            }
            __builtin_nontemporal_store(
                pk.u, (u16x4*)(Qo + (((size_t)((b * 16 + hh) * SEQ + n)) << 6) + d0));
          }
        }
      } else {
        // K/V block: m = token t, col = channel. 4 regs = 4 consecutive n.
#pragma unroll
        for (int nt = 0; nt < 4; ++nt) {
          const int ch  = bnv * 256 + wn * 64 + nt * 16 + lr;
          const int sel = ch >> 10;           // 1 = K, 2 = V
          const int hh  = (ch >> 6) & 15;
          const int d   = ch & 63;
          bf16* dst = (sel == 1) ? Ko : Vo;
#pragma unroll
          for (int mt = 0; mt < 8; ++mt) {
            const int t0 = bmv * 256 + wm * 128 + mt * 16 + lq * 4;
            const int b = t0 >> 12, n0 = t0 & 4095;
            union { bf16 v[4]; u16x4 u; } pk;
#pragma unroll
            for (int r = 0; r < 4; ++r) {
              float v = acc[mt][nt][r];
              if (sel == 1) v = (v > 0.0f) ? (v + 1.0f) : __expf(v);
              pk.v[r] = __float2bfloat16(v);
            }
            __builtin_nontemporal_store(
                pk.u, (u16x4*)(dst + ((size_t)((b * 16 + hh) * 64 + d)) * SEQ + n0));
          }
        }
      }
    } else {
      // proj: m = token t, col = channel. Coalesced fp32 nt stores + bias.
#pragma unroll
      for (int mt = 0; mt < 8; ++mt) {
#pragma unroll
        for (int r = 0; r < 4; ++r) {
          const int t = bmv * 256 + wm * 128 + mt * 16 + lq * 4 + r;
          float* op = Out + (size_t)t * CDIM + bnv * 256 + wn * 64 + lr;
#pragma unroll
          for (int nt = 0; nt < 4; ++nt)
            __builtin_nontemporal_store(
                acc[mt][nt][r] + bias[bnv * 256 + wn * 64 + nt * 16 + lr],
                op + nt * 16);
        }
      }
    }
  };

  // prologue: buf0 tile0 fully; buf1 {Ah0,Bh1,Ah1} (B1h0@64 comes at ph1, j=0)
  STA(A0, AgC, 0, 0);
  STB(B0, BgC, 0, 0);
  STB(B0, BgC, 0, 1);
  STA(A0, AgC, 0, 1);
  STA(A1, AgC, 64, 0);
  STB(B1, BgC, 64, 1);
  STA(A1, AgC, 64, 1);
  VMW6();            // all of buf0 (first 8 loads) landed
  BARR();

#pragma unroll 1
  for (int j = 0; j < 8 * NTILES - 1; ++j) {
    const int kl = (j & 7) << 7;
    const bf16* sA = AgC;
    const bf16* sB = BgC;
    int k1 = kl + 128, k2 = kl + 192;
    if (k1 == 1024) { sA = AgX; sB = BgX; k1 = 0; k2 = 64; }  // tile wrap
    FULL_ITER_BODY();
    if ((j & 7) == 7) {
      // tile t finished (its last MMA was ph8 above); next tile's first
      // K-tiles are already staged/in-flight. Store + reset, then advance.
      epilogue(bm, bn, swapped);
#pragma unroll
      for (int mi = 0; mi < 8; ++mi)
#pragma unroll
        for (int ni = 0; ni < 4; ++ni) acc[mi][ni] = (f32x4){0.f, 0.f, 0.f, 0.f};
      id += 256;
      bn = id % GNX; bm = id / GNX;
      swapped = (EPI == 0) && (bn < 4);
      AgC = AgX; BgC = BgX;
      const int idX = id + 256;                // may be OOB; never dereferenced
      const int bnX = idX % GNX, bmX = idX / GNX;
      const bool swX = (EPI == 0) && (bnX < 4);
      const bf16* XgX = X + (size_t)(bmX * 256) * K;
      const bf16* WgX = W + (size_t)(bnX * 256) * K;
      AgX = swX ? WgX : XgX;
      BgX = swX ? XgX : WgX;
    }
  }
  FINAL_ITER_BODY();
  epilogue(bm, bn, swapped);
}

// ---------------------------------------------------------------------------
// kv partials via MFMA.  Inputs K^T,V^T [bh][d][n] (n contiguous).
// Same T2 involution: LDS[row][c] = global[row][c ^ ((row&7)*8)].
// ---------------------------------------------------------------------------
__global__ __launch_bounds__(256) void kv_mfma(const bf16* __restrict__ KT,
                                               const bf16* __restrict__ VT,
                                               float* __restrict__ KVp,
                                               float* __restrict__ KSp) {
  __shared__ bf16 kt[64 * 64];
  __shared__ bf16 vt[64 * 64];
  const int tid = threadIdx.x;
  const int w = tid >> 6, lane = tid & 63;
  const int wm = w >> 1, wn = w & 1;
  const int lr = lane & 15, lq = lane >> 4;
  const int swz = (lr & 7) * 8;                            // read-side XOR
  const int csz = (((lane & 7) ^ (lane >> 3)) * 8);        // src-side pre-swizzle
  const int sp = blockIdx.x, bh = blockIdx.y;
  const bf16* kg0 = KT + (size_t)bh * 64 * SEQ + sp * 512;
  const bf16* vg0 = VT + (size_t)bh * 64 * SEQ + sp * 512;

  f32x4 acc[2][2] = {};
  f32x4 kacc0 = {}, kacc1 = {};
  short8 ones;
#pragma unroll
  for (int j = 0; j < 8; ++j) ((unsigned short*)&ones)[j] = 0x3F80;  // bf16 1.0

  for (int nc = 0; nc < 8; ++nc) {
    __syncthreads();
#pragma unroll
    for (int i = 0; i < 2; ++i) {
      const int row = w * 16 + i * 8 + (lane >> 3);
      async_load16(kg0 + (size_t)row * SEQ + nc * 64 + csz, kt + (w * 16 + i * 8) * 64);
      async_load16(vg0 + (size_t)row * SEQ + nc * 64 + csz, vt + (w * 16 + i * 8) * 64);
    }
    __syncthreads();

#pragma unroll
    for (int ks = 0; ks < 2; ++ks) {
      short8 a0 = *(const short8*)&kt[(wm * 32 +      lr) * 64 + ((ks * 32 + lq * 8) ^ swz)];
      short8 a1 = *(const short8*)&kt[(wm * 32 + 16 + lr) * 64 + ((ks * 32 + lq * 8) ^ swz)];
      short8 b0 = *(const short8*)&vt[(wn * 32 +      lr) * 64 + ((ks * 32 + lq * 8) ^ swz)];
      short8 b1 = *(const short8*)&vt[(wn * 32 + 16 + lr) * 64 + ((ks * 32 + lq * 8) ^ swz)];
      acc[0][0] = __builtin_amdgcn_mfma_f32_16x16x32_bf16(a0, b0, acc[0][0], 0, 0, 0);
      acc[0][1] = __builtin_amdgcn_mfma_f32_16x16x32_bf16(a0, b1, acc[0][1], 0, 0, 0);
      acc[1][0] = __builtin_amdgcn_mfma_f32_16x16x32_bf16(a1, b0, acc[1][0], 0, 0, 0);
      acc[1][1] = __builtin_amdgcn_mfma_f32_16x16x32_bf16(a1, b1, acc[1][1], 0, 0, 0);
      kacc0 = __builtin_amdgcn_mfma_f32_16x16x32_bf16(a0, ones, kacc0, 0, 0, 0);
      kacc1 = __builtin_amdgcn_mfma_f32_16x16x32_bf16(a1, ones, kacc1, 0, 0, 0);
    }
  }

  float* outp = KVp + ((size_t)(sp * 64 + bh)) * 4096;
#pragma unroll
  for (int mt = 0; mt < 2; ++mt)
#pragma unroll
    for (int nt = 0; nt < 2; ++nt) {
      const int e  = wn * 32 + nt * 16 + lr;
      const int d0 = wm * 32 + mt * 16 + lq * 4;
      *(float4*)&outp[e * 64 + d0] = *(float4*)&acc[mt][nt];
    }
  if (wn == 0 && lr == 0) {
    float* ksp = KSp + (size_t)(sp * 64 + bh) * 64 + wm * 32;
#pragma unroll
    for (int r = 0; r < 4; ++r) {
      ksp[lq * 4 + r]      = kacc0[r];
      ksp[16 + lq * 4 + r] = kacc1[r];
    }
  }
}

// ---------------------------------------------------------------------------
// reduce partials. grid 256 = (bh 64) x (quarter 4).
// ---------------------------------------------------------------------------
__global__ __launch_bounds__(256) void kv_reduce(const float* __restrict__ KVp,
                                                 const float* __restrict__ KSp,
                                                 bf16* __restrict__ KVT,
                                                 float* __restrict__ KS) {
  const int bh = blockIdx.x >> 2, q = blockIdx.x & 3, t = threadIdx.x;
#pragma unroll
  for (int i = 0; i < 4; ++i) {
    const int idx = (q * 4 + i) * 256 + t;
    float s = 0.0f;
#pragma unroll
    for (int sp = 0; sp < 8; ++sp) s += KVp[((size_t)(sp * 64 + bh)) * 4096 + idx];
    const bf16 hi = __float2bfloat16(s);
    const float lo = s - __bfloat162float(hi);
    const int e = idx >> 6, d = idx & 63;
    KVT[(size_t)bh * 8192 + e * 128 + d]      = hi;
    KVT[(size_t)bh * 8192 + e * 128 + 64 + d] = __float2bfloat16(lo);
  }
  if (q == 0 && t < 64) {
    float s = 0.0f;
#pragma unroll
    for (int sp = 0; sp < 8; ++sp) s += KSp[(sp * 64 + bh) * 64 + t];
    KS[bh * 64 + t] = s;
  }
}

// ---------------------------------------------------------------------------
// num = q @ kv. qs [128][64] and kvs [64][128] both carry the T2 involution
// LDS[row][c] = global[row][c ^ ((row&7)*8)] (chunk-granular, 8-elem chunks).
// ---------------------------------------------------------------------------
__global__ __launch_bounds__(256) void num_mfma(const bf16* __restrict__ Qb,
                                                const bf16* __restrict__ KVT,
                                                const float* __restrict__ KS,
                                                bf16* __restrict__ Attn) {
  __shared__ bf16 qs[128 * 64];
  __shared__ bf16 kvs[64 * 128];
  __shared__ bf16 Cs[128 * 72];
  __shared__ float ksl[64];
  __shared__ float dred[256];
  __shared__ float den[128];
  const int tid = threadIdx.x;
  const int w = tid >> 6, lane = tid & 63;
  const int wm = w >> 1, wn = w & 1;
  const int lr = lane & 15, lq = lane >> 4;
  const int swz = (lr & 7) * 8;
  const int bh = blockIdx.y, n00 = blockIdx.x * 128;
  const int b = bh >> 4, h = bh & 15;

  const bf16* qg  = Qb  + ((size_t)bh * SEQ + n00) * 64;
  const bf16* kvg = KVT + (size_t)bh * 8192;
  const int qcs = (((lane & 7) ^ (lane >> 3)) * 8);
#pragma unroll
  for (int i = 0; i < 4; ++i) {
    const int row = w * 32 + i * 8 + (lane >> 3);
    async_load16(qg + (size_t)row * 64 + qcs, qs + (w * 32 + i * 8) * 64);
  }
#pragma unroll
  for (int i = 0; i < 4; ++i) {
    const int row = w * 16 + i * 4 + (lane >> 4);
    const int scol = (((lane & 15) * 8) ^ ((row & 7) * 8));
    async_load16(kvg + (size_t)row * 128 + scol, kvs + (w * 16 + i * 4) * 128);
  }
  if (tid < 64) ksl[tid] = KS[bh * 64 + tid];
  __syncthreads();

  {
    const int n = tid >> 1, half = tid & 1;
    const int nsw = (n & 7) * 8;
    float s = 0.0f;
#pragma unroll
    for (int v8 = 0; v8 < 4; ++v8) {
      short8 qq = *(const short8*)&qs[n * 64 + ((half * 32 + v8 * 8) ^ nsw)];
#pragma unroll
      for (int j = 0; j < 8; ++j)
        s += __bfloat162float(((const bf16*)&qq)[j]) * ksl[half * 32 + v8 * 8 + j];
    }
    dred[tid] = s;
  }

  short8 afr[4][2], bfr2[2][4];
#pragma unroll
  for (int mt = 0; mt < 4; ++mt)
#pragma unroll
    for (int kh = 0; kh < 2; ++kh)
      afr[mt][kh] = *(const short8*)&qs[(wm * 64 + mt * 16 + lr) * 64 + ((kh * 32 + lq * 8) ^ swz)];
#pragma unroll
  for (int nt = 0; nt < 2; ++nt)
#pragma unroll
    for (int ks = 0; ks < 4; ++ks)
      bfr2[nt][ks] = *(const short8*)&kvs[(wn * 32 + nt * 16 + lr) * 128 + ((ks * 32 + lq * 8) ^ swz)];

  f32x4 acc[4][2] = {};
#pragma unroll
  for (int ks = 0; ks < 4; ++ks)
#pragma unroll
    for (int mt = 0; mt < 4; ++mt)
#pragma unroll
      for (int nt = 0; nt < 2; ++nt)
        acc[mt][nt] = __builtin_amdgcn_mfma_f32_16x16x32_bf16(afr[mt][ks & 1], bfr2[nt][ks],
                                                              acc[mt][nt], 0, 0, 0);
  __syncthreads();
  if (tid < 128) den[tid] = dred[tid * 2] + dred[tid * 2 + 1] + 1e-8f;
  __syncthreads();

#pragma unroll
  for (int mt = 0; mt < 4; ++mt) {
#pragma unroll
    for (int r = 0; r < 4; ++r) {
      const int nl = wm * 64 + mt * 16 + lq * 4 + r;
      const float inv = 1.0f / den[nl];
#pragma unroll
      for (int nt = 0; nt < 2; ++nt) {
        const int e = wn * 32 + nt * 16 + lr;
        Cs[nl * 72 + e] = __float2bfloat16(acc[mt][nt][r] * inv);
      }
    }
  }
  __syncthreads();
#pragma unroll
  for (int it = 0; it < 4; ++it) {
    const int nl = it * 32 + (tid >> 3);
    const int ch = tid & 7;
    short8 val = *(const short8*)&Cs[nl * 72 + ch * 8];
    *(short8*)(Attn + ((size_t)(b * SEQ + n00 + nl)) * CDIM + h * 64 + ch * 8) = val;
  }
}

// ---------------------------------------------------------------------------
extern "C" void kernel_launch(void* const* d_in, const int* in_sizes, int n_in,
                              void* d_out, int out_size, void* d_ws, size_t ws_size,
                              hipStream_t stream) {
  const float* x      = (const float*)d_in[0];
  const float* w_qkv  = (const float*)d_in[1];
  const float* w_proj = (const float*)d_in[2];
  const float* b_proj = (const float*)d_in[3];
  float* out = (float*)d_out;
  char* ws = (char*)d_ws;

  bf16*  xb     = (bf16*)(ws + 0);
  bf16*  wqkvb  = (bf16*)(ws + 33554432);
  bf16*  wprojb = (bf16*)(ws + 39845888);
  bf16*  qb     = (bf16*)(ws + 41943040);
  bf16*  ktb    = (bf16*)(ws + 75497472);
  bf16*  vtb    = (bf16*)(ws + 109051904);
  float* kvp    = (float*)(ws + 0);
  float* ksp    = (float*)(ws + 8388608);
  bf16*  kvt    = (bf16*)(ws + 142606336);
  float* ksum   = (float*)(ws + 143654912);
  bf16*  attn   = (bf16*)(ws + 0);

  convert3_kernel<<<20480, 256, 0, stream>>>(x, w_qkv, w_proj, xb, wqkvb, wprojb);

  gemm256<0, 3, 12><<<256, 512, 0, stream>>>(xb, wqkvb, nullptr, qb, ktb, vtb, nullptr, 1024);
  kv_mfma<<<dim3(8, 64), 256, 0, stream>>>(ktb, vtb, kvp, ksp);
  kv_reduce<<<256, 256, 0, stream>>>(kvp, ksp, kvt, ksum);
  num_mfma<<<dim3(32, 64), 256, 0, stream>>>(qb, kvt, ksum, attn);
  gemm256<1, 1, 4><<<256, 512, 0, stream>>>(attn, wprojb, b_proj, nullptr, nullptr, nullptr, out, 1024);
}

// Round 6
// 329.736 us; speedup vs baseline: 1.0349x; 1.0349x over previous
//
#include <hip/hip_runtime.h>
#include <hip/hip_bf16.h>
#include <stdint.h>

typedef __hip_bfloat16 bf16;
typedef __attribute__((ext_vector_type(4))) float f32x4;
typedef __attribute__((ext_vector_type(8))) short short8;

#define SEQ   4096
#define CDIM  1024

// ---------------------------------------------------------------------------
// async global->LDS, 16B per lane. LDS dest = wave-uniform base + lane*16.
// ---------------------------------------------------------------------------
__device__ __forceinline__ void async_load16(const void* g, void* l) {
  auto gp = reinterpret_cast<const __attribute__((address_space(1))) uint32_t*>(
      reinterpret_cast<uintptr_t>(g));
  auto lp = reinterpret_cast<__attribute__((address_space(3))) uint32_t*>(
      static_cast<uint32_t>(reinterpret_cast<uintptr_t>(l)));
  __builtin_amdgcn_global_load_lds(gp, lp, 16, 0, 0);
}

// ---------------------------------------------------------------------------
// fused fp32 -> bf16 convert for x, w_qkv, w_proj (one launch)
// ---------------------------------------------------------------------------
__global__ __launch_bounds__(256) void convert3_kernel(const float* __restrict__ x,
                                                       const float* __restrict__ wq,
                                                       const float* __restrict__ wp,
                                                       bf16* __restrict__ xb,
                                                       bf16* __restrict__ wqb,
                                                       bf16* __restrict__ wpb) {
  int i = blockIdx.x * 256 + threadIdx.x;
  const float* src;
  bf16* dst;
  int off;
  if (i < 4194304)      { src = x;  dst = xb;  off = i; }
  else if (i < 4980736) { src = wq; dst = wqb; off = i - 4194304; }
  else                  { src = wp; dst = wpb; off = i - 4980736; }
  float4 f = ((const float4*)src)[off];
  union { bf16 b[4]; ushort4 u; } c;
  c.b[0] = __float2bfloat16(f.x);
  c.b[1] = __float2bfloat16(f.y);
  c.b[2] = __float2bfloat16(f.z);
  c.b[3] = __float2bfloat16(f.w);
  ((ushort4*)dst)[off] = c.u;
}

// ---------------------------------------------------------------------------
// 256x256 8-phase bf16 GEMM with ds_read/MFMA OVERLAP.
//   C[m][n] = sum_k A[m][k] * B[n][k]   (both row-major, K-contiguous)
// 512 threads = 8 waves (2M x 4N); per-wave output 128x64; BK=64.
// LDS: A0,B0,A1,B1 each [256][64] bf16 = 128 KiB.
// T2 swizzle: LDS[row][c] = global[row][c ^ ((row&7)*8)] via pre-swizzled
// global src + matching XOR on ds_read (conflict-free, verified 0).
// T1: XCD-chunked bijective block remap (nwg % 8 == 0).
//
// NEW (this round): each phase's ds_reads are issued inside the PREVIOUS
// phase's MFMA region with counted lgkmcnt waits, so LDS service overlaps
// the matrix pipe (previously strictly serialized by the barrier lockstep).
// Phase p = [BARR; stage(p); (VMW+BARR at p4/p8); reads(p+1); lgkm(N);
//            sched_barrier; setprio1; MFMA(p); setprio0; (post-reads)].
// Hazard proof sketch (checked per region):
//  - overwrite side: every staged region's readers are lgkm-waited before
//    their consuming MFMA, hence before the barrier preceding the stage.
//  - retirement side: reads of staged data sit after a barrier preceded by
//    ALL waves' vmcnt(6) wait; staging stream is unchanged from R3, so the
//    "<=6 newest in flight" counts are identical.
// Registers: af[4][2] single set (h1 loads placed post-MFMA: WAR-pinned),
// b1r[2][2] single, b0r[2][2][2] double set (loaded during MMA(1,0)).
// ---------------------------------------------------------------------------
#define BARR()   __builtin_amdgcn_s_barrier()
#define LGKM0_() asm volatile("s_waitcnt lgkmcnt(0)" ::: "memory")
#define LGKM4_() asm volatile("s_waitcnt lgkmcnt(4)" ::: "memory")
#define VMW6()   asm volatile("s_waitcnt vmcnt(6)" ::: "memory")
#define VMW0()   asm volatile("s_waitcnt vmcnt(0)" ::: "memory")
#define SP(x)    __builtin_amdgcn_s_setprio(x)
#define SB0()    __builtin_amdgcn_sched_barrier(0)

// A half h: rows {h*64 + [0,64)} u {h*64+128 + [0,64)}; wave w stages 8 rows.
#define STA(buf, kc, h)                                                        \
  {                                                                            \
    const int ra_ = (h) * 64 + w * 8;                                          \
    async_load16(Ag + (size_t)(ra_ + lr8) * K + (kc) + cs, (buf) + ra_ * 64);  \
    async_load16(Ag + (size_t)(ra_ + 128 + lr8) * K + (kc) + cs,               \
                 (buf) + (ra_ + 128) * 64);                                    \
  }
// B half h: rows {wn'*64 + h*32 + [0,32) : wn'=0..3}; wave w stages 8 rows.
#define STB(buf, kc, h)                                                        \
  {                                                                            \
    const int rb_ = (w & 3) * 8 + (w >> 2) * 64 + (h) * 32;                    \
    async_load16(Bg + (size_t)(rb_ + lr8) * K + (kc) + cs, (buf) + rb_ * 64);  \
    async_load16(Bg + (size_t)(rb_ + 128 + lr8) * K + (kc) + cs,               \
                 (buf) + (rb_ + 128) * 64);                                    \
  }

// af <- buf A-half h (8 reads)
#define RD_AH(buf, h)                                                          \
  {                                                                            \
    _Pragma("unroll") for (int mi = 0; mi < 4; ++mi) {                         \
      const unsigned short* p_ = (buf) + (arow0 + (h) * 64 + mi * 16) * 64;    \
      af[mi][0] = *(const short8*)(p_ + ((lq * 8) ^ sw));                      \
      af[mi][1] = *(const short8*)(p_ + ((32 + lq * 8) ^ sw));                 \
    }                                                                          \
  }
// b1r <- buf B-half 1 (4 reads)
#define RD_B1(buf)                                                             \
  {                                                                            \
    _Pragma("unroll") for (int ni = 0; ni < 2; ++ni) {                         \
      const unsigned short* p_ = (buf) + (brow0 + 32 + ni * 16) * 64;          \
      b1r[ni][0] = *(const short8*)(p_ + ((lq * 8) ^ sw));                     \
      b1r[ni][1] = *(const short8*)(p_ + ((32 + lq * 8) ^ sw));                \
    }                                                                          \
  }
// b0r[S] <- buf B-half 0 (4 reads)
#define RD_B0S(buf, S)                                                         \
  {                                                                            \
    _Pragma("unroll") for (int ni = 0; ni < 2; ++ni) {                         \
      const unsigned short* p_ = (buf) + (brow0 + ni * 16) * 64;               \
      b0r[S][ni][0] = *(const short8*)(p_ + ((lq * 8) ^ sw));                  \
      b0r[S][ni][1] = *(const short8*)(p_ + ((32 + lq * 8) ^ sw));             \
    }                                                                          \
  }

// MFMA clusters: af holds the current m-quadrant (MQ), B operand selects NQ.
#define MMA_B0(MQ, S)                                                          \
  {                                                                            \
    _Pragma("unroll") for (int ks = 0; ks < 2; ++ks)                           \
      _Pragma("unroll") for (int mi = 0; mi < 4; ++mi)                         \
        _Pragma("unroll") for (int ni = 0; ni < 2; ++ni)                       \
          acc[(MQ) * 4 + mi][ni] = __builtin_amdgcn_mfma_f32_16x16x32_bf16(    \
              af[mi][ks], b0r[S][ni][ks], acc[(MQ) * 4 + mi][ni], 0, 0, 0);    \
  }
#define MMA_B1(MQ)                                                             \
  {                                                                            \
    _Pragma("unroll") for (int ks = 0; ks < 2; ++ks)                           \
      _Pragma("unroll") for (int mi = 0; mi < 4; ++mi)                         \
        _Pragma("unroll") for (int ni = 0; ni < 2; ++ni)                       \
          acc[(MQ) * 4 + mi][2 + ni] = __builtin_amdgcn_mfma_f32_16x16x32_bf16(\
              af[mi][ks], b1r[ni][ks], acc[(MQ) * 4 + mi][2 + ni], 0, 0, 0);   \
  }

// One iteration = 2 K-tiles (buf0 @ kc, buf1 @ kc+64); stages kc+128/kc+192.
#define FULL_ITER(kc)                                                          \
  BARR(); STB(B1, (kc) + 64, 0); RD_B1(B0);                                    \
  LGKM4_(); SB0(); SP(1); MMA_B0(0, 0); SP(0);                                 \
  BARR(); STA(A0, (kc) + 128, 0);                                              \
  LGKM0_(); SB0(); SP(1); MMA_B1(0); SP(0); RD_AH(A0, 1);                      \
  BARR(); STB(B0, (kc) + 128, 1);                                              \
  LGKM0_(); SB0(); SP(1); MMA_B1(1); SP(0);                                    \
  BARR(); STA(A0, (kc) + 128, 1); VMW6(); BARR(); RD_B0S(B1, 1);               \
  LGKM4_(); SB0(); SP(1); MMA_B0(1, 0); SP(0); RD_AH(A1, 0);                   \
  BARR(); STB(B0, (kc) + 128, 0); RD_B1(B1);                                   \
  LGKM4_(); SB0(); SP(1); MMA_B0(0, 1); SP(0);                                 \
  BARR(); STA(A1, (kc) + 192, 0);                                              \
  LGKM0_(); SB0(); SP(1); MMA_B1(0); SP(0); RD_AH(A1, 1);                      \
  BARR(); STB(B1, (kc) + 192, 1);                                              \
  LGKM0_(); SB0(); SP(1); MMA_B1(1); SP(0);                                    \
  BARR(); STA(A1, (kc) + 192, 1); VMW6(); BARR(); RD_B0S(B0, 0);               \
  LGKM4_(); SB0(); SP(1); MMA_B0(1, 1); SP(0); RD_AH(A0, 0);

// Final iteration (kc = 896): only B1h0@960 still needs staging; VMW0 drain.
#define FINAL_ITER()                                                           \
  BARR(); STB(B1, 960, 0); RD_B1(B0);                                          \
  LGKM4_(); SB0(); SP(1); MMA_B0(0, 0); SP(0);                                 \
  BARR(); LGKM0_(); SB0(); SP(1); MMA_B1(0); SP(0); RD_AH(A0, 1);              \
  BARR(); LGKM0_(); SB0(); SP(1); MMA_B1(1); SP(0);                            \
  BARR(); VMW0(); BARR(); RD_B0S(B1, 1);                                       \
  LGKM4_(); SB0(); SP(1); MMA_B0(1, 0); SP(0); RD_AH(A1, 0);                   \
  BARR(); RD_B1(B1);                                                           \
  LGKM4_(); SB0(); SP(1); MMA_B0(0, 1); SP(0);                                 \
  BARR(); LGKM0_(); SB0(); SP(1); MMA_B1(0); SP(0); RD_AH(A1, 1);              \
  BARR(); LGKM0_(); SB0(); SP(1); MMA_B1(1); SP(0);                            \
  BARR(); LGKM0_(); SB0(); SP(1); MMA_B0(1, 1); SP(0);

template <int EPI>
__global__ __launch_bounds__(512, 2) void gemm256(const bf16* __restrict__ X,
                                                  const bf16* __restrict__ W,
                                                  const float* __restrict__ bias,
                                                  bf16* __restrict__ Qo,
                                                  bf16* __restrict__ Ko,
                                                  bf16* __restrict__ Vo,
                                                  float* __restrict__ Out,
                                                  const int K) {
  __shared__ __attribute__((aligned(16))) unsigned short lds[4][256 * 64];
  unsigned short* const A0 = lds[0];
  unsigned short* const B0 = lds[1];
  unsigned short* const A1 = lds[2];
  unsigned short* const B1 = lds[3];

  const int tid  = threadIdx.x;
  const int w    = tid >> 6, lane = tid & 63;
  const int wm   = w >> 2,   wn   = w & 3;
  const int lr   = lane & 15, lq  = lane >> 4;

  // T1: XCD-chunked bijective remap (nwg % 8 == 0 for both grids).
  const int GX   = (int)gridDim.x;
  const int nwg  = GX * (int)gridDim.y;
  const int lin  = (int)blockIdx.y * GX + (int)blockIdx.x;
  const int tile = (lin & 7) * (nwg >> 3) + (lin >> 3);
  const int bn   = tile % GX;
  const int bm   = tile / GX;

  const int sw   = (lr & 7) << 3;                          // read-side XOR (elems)
  const int cs   = (((lane & 7) ^ (lane >> 3)) << 3);      // src-side pre-swizzle
  const int lr8  = lane >> 3;

  const bool swapped = (EPI == 0) && (bn < 4);
  const bf16* Xg = X + (size_t)(bm * 256) * K;
  const bf16* Wg = W + (size_t)(bn * 256) * K;
  const bf16* Ag = swapped ? Wg : Xg;
  const bf16* Bg = swapped ? Xg : Wg;

  const int arow0 = wm * 128 + lr;
  const int brow0 = wn * 64 + lr;

  short8 af[4][2];        // current m-quadrant A fragments (h0 or h1)
  short8 b1r[2][2];       // B half-1 fragments (single set)
  short8 b0r[2][2][2];    // B half-0 fragments (double set, toggles per K-tile)
  f32x4 acc[8][4] = {};

  // prologue: buf0 tile0 fully; buf1 {Ah0,Bh1,Ah1} (B1h0@64 staged at P1, j=0)
  STA(A0, 0, 0);
  STB(B0, 0, 0);
  STB(B0, 0, 1);
  STA(A0, 0, 1);
  STA(A1, 64, 0);
  STB(B1, 64, 1);
  STA(A1, 64, 1);
  VMW6();            // first 8 ops (all of buf0) retired
  BARR();
  RD_AH(A0, 0);      // initial fragments for P1
  RD_B0S(B0, 0);

#pragma unroll 1
  for (int kc = 0; kc < K - 128; kc += 128) {
    FULL_ITER(kc);
  }
  FINAL_ITER();

  // ------------------------- epilogue -------------------------
  if constexpr (EPI == 0) {
    if (swapped) {
      // Q block: m = channel j, col = token t. 4 regs = 4 consecutive d.
#pragma unroll
      for (int mt = 0; mt < 8; ++mt) {
        const int j0 = bn * 256 + wm * 128 + mt * 16 + lq * 4;
        const int h  = j0 >> 6, d0 = j0 & 63;
#pragma unroll
        for (int nt = 0; nt < 4; ++nt) {
          const int t = bm * 256 + wn * 64 + nt * 16 + lr;
          const int b = t >> 12, n = t & 4095;
          union { bf16 v[4]; ushort4 u; } pk;
#pragma unroll
          for (int r = 0; r < 4; ++r) {
            float v = acc[mt][nt][r];
            v = (v > 0.0f) ? (v + 1.0f) : __expf(v);
            pk.v[r] = __float2bfloat16(v);
          }
          *(ushort4*)(Qo + (((size_t)((b * 16 + h) * SEQ + n)) << 6) + d0) = pk.u;
        }
      }
    } else {
      // K/V block: m = token t, col = channel j. 4 regs = 4 consecutive n.
#pragma unroll
      for (int nt = 0; nt < 4; ++nt) {
        const int j   = bn * 256 + wn * 64 + nt * 16 + lr;
        const int sel = j >> 10;           // 1 = K, 2 = V
        const int h   = (j >> 6) & 15;
        const int d   = j & 63;
        bf16* dst = (sel == 1) ? Ko : Vo;
#pragma unroll
        for (int mt = 0; mt < 8; ++mt) {
          const int t0 = bm * 256 + wm * 128 + mt * 16 + lq * 4;
          const int b = t0 >> 12, n0 = t0 & 4095;
          union { bf16 v[4]; ushort4 u; } pk;
#pragma unroll
          for (int r = 0; r < 4; ++r) {
            float v = acc[mt][nt][r];
            if (sel == 1) v = (v > 0.0f) ? (v + 1.0f) : __expf(v);
            pk.v[r] = __float2bfloat16(v);
          }
          *(ushort4*)(dst + ((size_t)((b * 16 + h) * 64 + d)) * SEQ + n0) = pk.u;
        }
      }
    }
  } else {
    // proj: m = token t, col = channel. Coalesced scalar fp32 stores + bias.
#pragma unroll
    for (int mt = 0; mt < 8; ++mt) {
#pragma unroll
      for (int r = 0; r < 4; ++r) {
        const int t = bm * 256 + wm * 128 + mt * 16 + lq * 4 + r;
        float* op = Out + (size_t)t * CDIM + bn * 256 + wn * 64 + lr;
#pragma unroll
        for (int nt = 0; nt < 4; ++nt)
          op[nt * 16] = acc[mt][nt][r] + bias[bn * 256 + wn * 64 + nt * 16 + lr];
      }
    }
  }
}

// ---------------------------------------------------------------------------
// kv partials via MFMA.  Inputs K^T,V^T [bh][d][n] (n contiguous).
// Same T2 involution: LDS[row][c] = global[row][c ^ ((row&7)*8)].
// ---------------------------------------------------------------------------
__global__ __launch_bounds__(256) void kv_mfma(const bf16* __restrict__ KT,
                                               const bf16* __restrict__ VT,
                                               float* __restrict__ KVp,
                                               float* __restrict__ KSp) {
  __shared__ bf16 kt[64 * 64];
  __shared__ bf16 vt[64 * 64];
  const int tid = threadIdx.x;
  const int w = tid >> 6, lane = tid & 63;
  const int wm = w >> 1, wn = w & 1;
  const int lr = lane & 15, lq = lane >> 4;
  const int swz = (lr & 7) * 8;                            // read-side XOR
  const int csz = (((lane & 7) ^ (lane >> 3)) * 8);        // src-side pre-swizzle
  const int sp = blockIdx.x, bh = blockIdx.y;
  const bf16* kg0 = KT + (size_t)bh * 64 * SEQ + sp * 512;
  const bf16* vg0 = VT + (size_t)bh * 64 * SEQ + sp * 512;

  f32x4 acc[2][2] = {};
  f32x4 kacc0 = {}, kacc1 = {};
  short8 ones;
#pragma unroll
  for (int j = 0; j < 8; ++j) ((unsigned short*)&ones)[j] = 0x3F80;  // bf16 1.0

  for (int nc = 0; nc < 8; ++nc) {
    __syncthreads();
#pragma unroll
    for (int i = 0; i < 2; ++i) {
      const int row = w * 16 + i * 8 + (lane >> 3);
      async_load16(kg0 + (size_t)row * SEQ + nc * 64 + csz, kt + (w * 16 + i * 8) * 64);
      async_load16(vg0 + (size_t)row * SEQ + nc * 64 + csz, vt + (w * 16 + i * 8) * 64);
    }
    __syncthreads();

#pragma unroll
    for (int ks = 0; ks < 2; ++ks) {
      short8 a0 = *(const short8*)&kt[(wm * 32 +      lr) * 64 + ((ks * 32 + lq * 8) ^ swz)];
      short8 a1 = *(const short8*)&kt[(wm * 32 + 16 + lr) * 64 + ((ks * 32 + lq * 8) ^ swz)];
      short8 b0 = *(const short8*)&vt[(wn * 32 +      lr) * 64 + ((ks * 32 + lq * 8) ^ swz)];
      short8 b1 = *(const short8*)&vt[(wn * 32 + 16 + lr) * 64 + ((ks * 32 + lq * 8) ^ swz)];
      acc[0][0] = __builtin_amdgcn_mfma_f32_16x16x32_bf16(a0, b0, acc[0][0], 0, 0, 0);
      acc[0][1] = __builtin_amdgcn_mfma_f32_16x16x32_bf16(a0, b1, acc[0][1], 0, 0, 0);
      acc[1][0] = __builtin_amdgcn_mfma_f32_16x16x32_bf16(a1, b0, acc[1][0], 0, 0, 0);
      acc[1][1] = __builtin_amdgcn_mfma_f32_16x16x32_bf16(a1, b1, acc[1][1], 0, 0, 0);
      kacc0 = __builtin_amdgcn_mfma_f32_16x16x32_bf16(a0, ones, kacc0, 0, 0, 0);
      kacc1 = __builtin_amdgcn_mfma_f32_16x16x32_bf16(a1, ones, kacc1, 0, 0, 0);
    }
  }

  float* outp = KVp + ((size_t)(sp * 64 + bh)) * 4096;
#pragma unroll
  for (int mt = 0; mt < 2; ++mt)
#pragma unroll
    for (int nt = 0; nt < 2; ++nt) {
      const int e  = wn * 32 + nt * 16 + lr;
      const int d0 = wm * 32 + mt * 16 + lq * 4;
      *(float4*)&outp[e * 64 + d0] = *(float4*)&acc[mt][nt];
    }
  if (wn == 0 && lr == 0) {
    float* ksp = KSp + (size_t)(sp * 64 + bh) * 64 + wm * 32;
#pragma unroll
    for (int r = 0; r < 4; ++r) {
      ksp[lq * 4 + r]      = kacc0[r];
      ksp[16 + lq * 4 + r] = kacc1[r];
    }
  }
}

// ---------------------------------------------------------------------------
// reduce partials. grid 256 = (bh 64) x (quarter 4).
// ---------------------------------------------------------------------------
__global__ __launch_bounds__(256) void kv_reduce(const float* __restrict__ KVp,
                                                 const float* __restrict__ KSp,
                                                 bf16* __restrict__ KVT,
                                                 float* __restrict__ KS) {
  const int bh = blockIdx.x >> 2, q = blockIdx.x & 3, t = threadIdx.x;
#pragma unroll
  for (int i = 0; i < 4; ++i) {
    const int idx = (q * 4 + i) * 256 + t;
    float s = 0.0f;
#pragma unroll
    for (int sp = 0; sp < 8; ++sp) s += KVp[((size_t)(sp * 64 + bh)) * 4096 + idx];
    const bf16 hi = __float2bfloat16(s);
    const float lo = s - __bfloat162float(hi);
    const int e = idx >> 6, d = idx & 63;
    KVT[(size_t)bh * 8192 + e * 128 + d]      = hi;
    KVT[(size_t)bh * 8192 + e * 128 + 64 + d] = __float2bfloat16(lo);
  }
  if (q == 0 && t < 64) {
    float s = 0.0f;
#pragma unroll
    for (int sp = 0; sp < 8; ++sp) s += KSp[(sp * 64 + bh) * 64 + t];
    KS[bh * 64 + t] = s;
  }
}

// ---------------------------------------------------------------------------
// num = q @ kv. qs [128][64] and kvs [64][128] both carry the T2 involution
// LDS[row][c] = global[row][c ^ ((row&7)*8)] (chunk-granular, 8-elem chunks).
// ---------------------------------------------------------------------------
__global__ __launch_bounds__(256) void num_mfma(const bf16* __restrict__ Qb,
                                                const bf16* __restrict__ KVT,
                                                const float* __restrict__ KS,
                                                bf16* __restrict__ Attn) {
  __shared__ bf16 qs[128 * 64];
  __shared__ bf16 kvs[64 * 128];
  __shared__ bf16 Cs[128 * 72];
  __shared__ float ksl[64];
  __shared__ float dred[256];
  __shared__ float den[128];
  const int tid = threadIdx.x;
  const int w = tid >> 6, lane = tid & 63;
  const int wm = w >> 1, wn = w & 1;
  const int lr = lane & 15, lq = lane >> 4;
  const int swz = (lr & 7) * 8;
  const int bh = blockIdx.y, n00 = blockIdx.x * 128;
  const int b = bh >> 4, h = bh & 15;

  const bf16* qg  = Qb  + ((size_t)bh * SEQ + n00) * 64;
  const bf16* kvg = KVT + (size_t)bh * 8192;
  const int qcs = (((lane & 7) ^ (lane >> 3)) * 8);
#pragma unroll
  for (int i = 0; i < 4; ++i) {
    const int row = w * 32 + i * 8 + (lane >> 3);
    async_load16(qg + (size_t)row * 64 + qcs, qs + (w * 32 + i * 8) * 64);
  }
#pragma unroll
  for (int i = 0; i < 4; ++i) {
    const int row = w * 16 + i * 4 + (lane >> 4);
    const int scol = (((lane & 15) * 8) ^ ((row & 7) * 8));
    async_load16(kvg + (size_t)row * 128 + scol, kvs + (w * 16 + i * 4) * 128);
  }
  if (tid < 64) ksl[tid] = KS[bh * 64 + tid];
  __syncthreads();

  {
    const int n = tid >> 1, half = tid & 1;
    const int nsw = (n & 7) * 8;
    float s = 0.0f;
#pragma unroll
    for (int v8 = 0; v8 < 4; ++v8) {
      short8 qq = *(const short8*)&qs[n * 64 + ((half * 32 + v8 * 8) ^ nsw)];
#pragma unroll
      for (int j = 0; j < 8; ++j)
        s += __bfloat162float(((const bf16*)&qq)[j]) * ksl[half * 32 + v8 * 8 + j];
    }
    dred[tid] = s;
  }

  short8 afr[4][2], bfr2[2][4];
#pragma unroll
  for (int mt = 0; mt < 4; ++mt)
#pragma unroll
    for (int kh = 0; kh < 2; ++kh)
      afr[mt][kh] = *(const short8*)&qs[(wm * 64 + mt * 16 + lr) * 64 + ((kh * 32 + lq * 8) ^ swz)];
#pragma unroll
  for (int nt = 0; nt < 2; ++nt)
#pragma unroll
    for (int ks = 0; ks < 4; ++ks)
      bfr2[nt][ks] = *(const short8*)&kvs[(wn * 32 + nt * 16 + lr) * 128 + ((ks * 32 + lq * 8) ^ swz)];

  f32x4 acc[4][2] = {};
#pragma unroll
  for (int ks = 0; ks < 4; ++ks)
#pragma unroll
    for (int mt = 0; mt < 4; ++mt)
#pragma unroll
      for (int nt = 0; nt < 2; ++nt)
        acc[mt][nt] = __builtin_amdgcn_mfma_f32_16x16x32_bf16(afr[mt][ks & 1], bfr2[nt][ks],
                                                              acc[mt][nt], 0, 0, 0);
  __syncthreads();
  if (tid < 128) den[tid] = dred[tid * 2] + dred[tid * 2 + 1] + 1e-8f;
  __syncthreads();

#pragma unroll
  for (int mt = 0; mt < 4; ++mt) {
#pragma unroll
    for (int r = 0; r < 4; ++r) {
      const int nl = wm * 64 + mt * 16 + lq * 4 + r;
      const float inv = 1.0f / den[nl];
#pragma unroll
      for (int nt = 0; nt < 2; ++nt) {
        const int e = wn * 32 + nt * 16 + lr;
        Cs[nl * 72 + e] = __float2bfloat16(acc[mt][nt][r] * inv);
      }
    }
  }
  __syncthreads();
#pragma unroll
  for (int it = 0; it < 4; ++it) {
    const int nl = it * 32 + (tid >> 3);
    const int ch = tid & 7;
    short8 val = *(const short8*)&Cs[nl * 72 + ch * 8];
    *(short8*)(Attn + ((size_t)(b * SEQ + n00 + nl)) * CDIM + h * 64 + ch * 8) = val;
  }
}

// ---------------------------------------------------------------------------
extern "C" void kernel_launch(void* const* d_in, const int* in_sizes, int n_in,
                              void* d_out, int out_size, void* d_ws, size_t ws_size,
                              hipStream_t stream) {
  const float* x      = (const float*)d_in[0];
  const float* w_qkv  = (const float*)d_in[1];
  const float* w_proj = (const float*)d_in[2];
  const float* b_proj = (const float*)d_in[3];
  float* out = (float*)d_out;
  char* ws = (char*)d_ws;

  bf16*  xb     = (bf16*)(ws + 0);
  bf16*  wqkvb  = (bf16*)(ws + 33554432);
  bf16*  wprojb = (bf16*)(ws + 39845888);
  bf16*  qb     = (bf16*)(ws + 41943040);
  bf16*  ktb    = (bf16*)(ws + 75497472);
  bf16*  vtb    = (bf16*)(ws + 109051904);
  float* kvp    = (float*)(ws + 0);
  float* ksp    = (float*)(ws + 8388608);
  bf16*  kvt    = (bf16*)(ws + 142606336);
  float* ksum   = (float*)(ws + 143654912);
  bf16*  attn   = (bf16*)(ws + 0);

  convert3_kernel<<<20480, 256, 0, stream>>>(x, w_qkv, w_proj, xb, wqkvb, wprojb);

  gemm256<0><<<dim3(12, 64), 512, 0, stream>>>(xb, wqkvb, nullptr, qb, ktb, vtb, nullptr, 1024);
  kv_mfma<<<dim3(8, 64), 256, 0, stream>>>(ktb, vtb, kvp, ksp);
  kv_reduce<<<256, 256, 0, stream>>>(kvp, ksp, kvt, ksum);
  num_mfma<<<dim3(32, 64), 256, 0, stream>>>(qb, kvt, ksum, attn);
  gemm256<1><<<dim3(4, 64), 512, 0, stream>>>(attn, wprojb, b_proj, nullptr, nullptr, nullptr, out, 1024);
}

// Round 7
// 305.678 us; speedup vs baseline: 1.1163x; 1.0787x over previous
//
#include <hip/hip_runtime.h>
#include <hip/hip_bf16.h>
#include <stdint.h>

typedef __hip_bfloat16 bf16;
typedef __attribute__((ext_vector_type(4))) float f32x4;
typedef __attribute__((ext_vector_type(8))) short short8;

#define SEQ   4096
#define CDIM  1024

// ---------------------------------------------------------------------------
// async global->LDS, 16B per lane. LDS dest = wave-uniform base + lane*16.
// ---------------------------------------------------------------------------
__device__ __forceinline__ void async_load16(const void* g, void* l) {
  auto gp = reinterpret_cast<const __attribute__((address_space(1))) uint32_t*>(
      reinterpret_cast<uintptr_t>(g));
  auto lp = reinterpret_cast<__attribute__((address_space(3))) uint32_t*>(
      static_cast<uint32_t>(reinterpret_cast<uintptr_t>(l)));
  __builtin_amdgcn_global_load_lds(gp, lp, 16, 0, 0);
}

// ---------------------------------------------------------------------------
// fused fp32 -> bf16 convert for x, w_qkv, w_proj (one launch)
// ---------------------------------------------------------------------------
__global__ __launch_bounds__(256) void convert3_kernel(const float* __restrict__ x,
                                                       const float* __restrict__ wq,
                                                       const float* __restrict__ wp,
                                                       bf16* __restrict__ xb,
                                                       bf16* __restrict__ wqb,
                                                       bf16* __restrict__ wpb) {
  int i = blockIdx.x * 256 + threadIdx.x;
  const float* src;
  bf16* dst;
  int off;
  if (i < 4194304)      { src = x;  dst = xb;  off = i; }
  else if (i < 4980736) { src = wq; dst = wqb; off = i - 4194304; }
  else                  { src = wp; dst = wpb; off = i - 4980736; }
  float4 f = ((const float4*)src)[off];
  union { bf16 b[4]; ushort4 u; } c;
  c.b[0] = __float2bfloat16(f.x);
  c.b[1] = __float2bfloat16(f.y);
  c.b[2] = __float2bfloat16(f.z);
  c.b[3] = __float2bfloat16(f.w);
  ((ushort4*)dst)[off] = c.u;
}

// ---------------------------------------------------------------------------
// 256x256 8-phase bf16 GEMM (R3 lockstep schedule), TILE-CHAINED v2.
//   C[m][n] = sum_k A[m][k] * B[n][k]   (both row-major, K-contiguous)
// 512 threads = 8 waves (2M x 4N); per-wave output 128x64; BK=64.
// LDS: A0,B0,A1,B1 each [256][64] bf16 = 128 KiB (1 block/CU).
// T2: LDS[row][c] = global[row][c ^ ((row&7)*8)] via pre-swizzled global src
// + matching XOR on ds_read (verified conflict-free: 0).
// Chain v2 (fixes R5): chain = bn-TRIPLE at FIXED bm (X panel reused across
// all 3 tiles, in-cache); chain->XCD map c=(b&7)*32+(b>>3) puts all 4 triples
// of each X-panel on one XCD (X fetched ~once from HBM). PLAIN stores only
// (R5's nt-stores caused 2x HBM write amplification + slow vmcnt drains).
// K stream is continuous (0..1023 x NTILES); at wrap iterations the +128/+192
// stages come from the NEXT tile's base (offsets 0/64) — region timing
// identical, vmcnt(6)-at-ph4/ph8 proof unchanged (R5 verified correct).
// Epilogue + acc reset run between wrap iterations while the next tile's
// staging is in flight (fill/drain paid once per block, not per tile).
// ---------------------------------------------------------------------------
#define BARR()  __builtin_amdgcn_s_barrier()
#define LGKM0() asm volatile("s_waitcnt lgkmcnt(0)" ::: "memory")
#define VMW6()  asm volatile("s_waitcnt vmcnt(6)" ::: "memory")
#define VMW0()  asm volatile("s_waitcnt vmcnt(0)" ::: "memory")
#define SP(x)   __builtin_amdgcn_s_setprio(x)

// A half h: rows {h*64 + [0,64)} u {h*64+128 + [0,64)}; wave w stages 8 rows.
#define STA(buf, base, kc, h)                                                  \
  {                                                                            \
    const int ra_ = (h) * 64 + w * 8;                                          \
    async_load16((base) + (size_t)(ra_ + lr8) * K + (kc) + cs,                 \
                 (buf) + ra_ * 64);                                            \
    async_load16((base) + (size_t)(ra_ + 128 + lr8) * K + (kc) + cs,           \
                 (buf) + (ra_ + 128) * 64);                                    \
  }
// B half h: rows {wn'*64 + h*32 + [0,32) : wn'=0..3}; wave w stages 8 rows.
#define STB(buf, base, kc, h)                                                  \
  {                                                                            \
    const int rb_ = (w & 3) * 8 + (w >> 2) * 64 + (h) * 32;                    \
    async_load16((base) + (size_t)(rb_ + lr8) * K + (kc) + cs,                 \
                 (buf) + rb_ * 64);                                            \
    async_load16((base) + (size_t)(rb_ + 128 + lr8) * K + (kc) + cs,           \
                 (buf) + (rb_ + 128) * 64);                                    \
  }

#define RD_A(buf, h)                                                           \
  {                                                                            \
    _Pragma("unroll") for (int mi = 0; mi < 4; ++mi) {                         \
      const unsigned short* p_ = (buf) + (arow0 + (h) * 64 + mi * 16) * 64;    \
      af[mi][0] = *(const short8*)(p_ + ((lq * 8) ^ sw));                      \
      af[mi][1] = *(const short8*)(p_ + ((32 + lq * 8) ^ sw));                 \
    }                                                                          \
  }
#define RD_B(buf, h)                                                           \
  {                                                                            \
    _Pragma("unroll") for (int ni = 0; ni < 2; ++ni) {                         \
      const unsigned short* p_ = (buf) + (brow0 + (h) * 32 + ni * 16) * 64;    \
      bfr[h][ni][0] = *(const short8*)(p_ + ((lq * 8) ^ sw));                  \
      bfr[h][ni][1] = *(const short8*)(p_ + ((32 + lq * 8) ^ sw));             \
    }                                                                          \
  }

#define MMA(MQ, NQ)                                                            \
  {                                                                            \
    _Pragma("unroll") for (int ks = 0; ks < 2; ++ks)                           \
      _Pragma("unroll") for (int mi = 0; mi < 4; ++mi)                         \
        _Pragma("unroll") for (int ni = 0; ni < 2; ++ni)                       \
          acc[(MQ) * 4 + mi][(NQ) * 2 + ni] =                                  \
              __builtin_amdgcn_mfma_f32_16x16x32_bf16(                         \
                  af[mi][ks], bfr[NQ][ni][ks],                                 \
                  acc[(MQ) * 4 + mi][(NQ) * 2 + ni], 0, 0, 0);                 \
  }

// full iteration: compute buf0 [ph1-4], buf1 [ph5-8]; stage kl+64 B1h0 (cur),
// (k1 -> buf0) and (k2 -> buf1 parts) from sA/sB (next tile at wrap).
#define FULL_ITER_BODY()                                                       \
  RD_A(A0, 0); RD_B(B0, 0); STB(B1, BgC, kl + 64, 0);                          \
  BARR(); LGKM0(); SP(1); MMA(0, 0); SP(0); BARR();                            \
  RD_B(B0, 1); STA(A0, sA, k1, 0);                                             \
  BARR(); LGKM0(); SP(1); MMA(0, 1); SP(0); BARR();                            \
  RD_A(A0, 1); STB(B0, sB, k1, 1);                                             \
  BARR(); LGKM0(); SP(1); MMA(1, 1); SP(0); BARR();                            \
  STA(A0, sA, k1, 1); VMW6();                                                  \
  BARR(); SP(1); MMA(1, 0); SP(0); BARR();                                     \
  RD_A(A1, 0); RD_B(B1, 0); STB(B0, sB, k1, 0);                                \
  BARR(); LGKM0(); SP(1); MMA(0, 0); SP(0); BARR();                            \
  RD_B(B1, 1); STA(A1, sA, k2, 0);                                             \
  BARR(); LGKM0(); SP(1); MMA(0, 1); SP(0); BARR();                            \
  RD_A(A1, 1); STB(B1, sB, k2, 1);                                             \
  BARR(); LGKM0(); SP(1); MMA(1, 1); SP(0); BARR();                            \
  STA(A1, sA, k2, 1); VMW6();                                                  \
  BARR(); SP(1); MMA(1, 0); SP(0); BARR();

// last iteration of the last tile: only B1h0@960 still needs staging.
#define FINAL_ITER_BODY()                                                      \
  RD_A(A0, 0); RD_B(B0, 0); STB(B1, BgC, 960, 0);                              \
  BARR(); LGKM0(); SP(1); MMA(0, 0); SP(0); BARR();                            \
  RD_B(B0, 1);                                                                 \
  BARR(); LGKM0(); SP(1); MMA(0, 1); SP(0); BARR();                            \
  RD_A(A0, 1);                                                                 \
  BARR(); LGKM0(); SP(1); MMA(1, 1); SP(0); BARR();                            \
  VMW0();                                                                      \
  BARR(); SP(1); MMA(1, 0); SP(0); BARR();                                     \
  RD_A(A1, 0); RD_B(B1, 0);                                                    \
  BARR(); LGKM0(); SP(1); MMA(0, 0); SP(0); BARR();                            \
  RD_B(B1, 1);                                                                 \
  BARR(); LGKM0(); SP(1); MMA(0, 1); SP(0); BARR();                            \
  RD_A(A1, 1);                                                                 \
  BARR(); LGKM0(); SP(1); MMA(1, 1); SP(0); BARR();                            \
  SP(1); MMA(1, 0); SP(0);

// EPI=0: NTILES=3, chain over bn-triple {3t,3t+1,3t+2} at fixed bm.
// EPI=1: NTILES=1, flat 256 tiles (bn = c&3, bm = c>>2), chain inert.
template <int EPI, int NTILES>
__global__ __launch_bounds__(512, 2) void gemm256(const bf16* __restrict__ X,
                                                  const bf16* __restrict__ W,
                                                  const float* __restrict__ bias,
                                                  bf16* __restrict__ Qo,
                                                  bf16* __restrict__ Ko,
                                                  bf16* __restrict__ Vo,
                                                  float* __restrict__ Out,
                                                  const int K) {
  __shared__ __attribute__((aligned(16))) unsigned short lds[4][256 * 64];
  unsigned short* const A0 = lds[0];
  unsigned short* const B0 = lds[1];
  unsigned short* const A1 = lds[2];
  unsigned short* const B1 = lds[3];

  const int tid  = threadIdx.x;
  const int w    = tid >> 6, lane = tid & 63;
  const int wm   = w >> 2,   wn   = w & 3;
  const int lr   = lane & 15, lq  = lane >> 4;

  const int sw   = (lr & 7) << 3;                          // read-side XOR (elems)
  const int cs   = (((lane & 7) ^ (lane >> 3)) << 3);      // src-side pre-swizzle
  const int lr8  = lane >> 3;

  const int arow0 = wm * 128 + lr;
  const int brow0 = wn * 64 + lr;

  // XCD-chunked chain map: block b -> chain c; XCD x owns bm in [8x, 8x+8).
  const int b_  = (int)blockIdx.x;
  const int c_  = (b_ & 7) * 32 + (b_ >> 3);
  const int bm  = c_ >> 2;
  int bn        = (EPI == 0) ? (c_ & 3) * 3 : (c_ & 3);

  bool swapped = (EPI == 0) && (bn < 4);
  const bf16* Xg = X + (size_t)(bm * 256) * K;   // fixed all chain (bm const)
  const bf16* AgC;
  const bf16* BgC;
  const bf16* AgX;
  const bf16* BgX;
  {
    const bf16* Wg = W + (size_t)(bn * 256) * K;
    AgC = swapped ? Wg : Xg;
    BgC = swapped ? Xg : Wg;
    const bool swX = (EPI == 0) && ((bn + 1) < 4);   // next tile (may be unused)
    const bf16* WgX = W + (size_t)((bn + 1) * 256) * K;
    AgX = swX ? WgX : Xg;
    BgX = swX ? Xg : WgX;
  }

  short8 af[4][2], bfr[2][2][2];   // bfr[half][ni][ks]
  f32x4 acc[8][4] = {};

  auto epilogue = [&](int bnv, bool swv) {
    if constexpr (EPI == 0) {
      if (swv) {
        // Q block: m = channel j, col = token t. 4 regs = 4 consecutive d.
#pragma unroll
        for (int mt = 0; mt < 8; ++mt) {
          const int j0 = bnv * 256 + wm * 128 + mt * 16 + lq * 4;
          const int hh = j0 >> 6, d0 = j0 & 63;
#pragma unroll
          for (int nt = 0; nt < 4; ++nt) {
            const int t = bm * 256 + wn * 64 + nt * 16 + lr;
            const int bb = t >> 12, n = t & 4095;
            union { bf16 v[4]; ushort4 u; } pk;
#pragma unroll
            for (int r = 0; r < 4; ++r) {
              float v = acc[mt][nt][r];
              v = (v > 0.0f) ? (v + 1.0f) : __expf(v);
              pk.v[r] = __float2bfloat16(v);
            }
            *(ushort4*)(Qo + (((size_t)((bb * 16 + hh) * SEQ + n)) << 6) + d0) = pk.u;
          }
        }
      } else {
        // K/V block: m = token t, col = channel. 4 regs = 4 consecutive n.
#pragma unroll
        for (int nt = 0; nt < 4; ++nt) {
          const int ch  = bnv * 256 + wn * 64 + nt * 16 + lr;
          const int sel = ch >> 10;           // 1 = K, 2 = V
          const int hh  = (ch >> 6) & 15;
          const int d   = ch & 63;
          bf16* dst = (sel == 1) ? Ko : Vo;
#pragma unroll
          for (int mt = 0; mt < 8; ++mt) {
            const int t0 = bm * 256 + wm * 128 + mt * 16 + lq * 4;
            const int bb = t0 >> 12, n0 = t0 & 4095;
            union { bf16 v[4]; ushort4 u; } pk;
#pragma unroll
            for (int r = 0; r < 4; ++r) {
              float v = acc[mt][nt][r];
              if (sel == 1) v = (v > 0.0f) ? (v + 1.0f) : __expf(v);
              pk.v[r] = __float2bfloat16(v);
            }
            *(ushort4*)(dst + ((size_t)((bb * 16 + hh) * 64 + d)) * SEQ + n0) = pk.u;
          }
        }
      }
    } else {
      // proj: m = token t, col = channel. Coalesced scalar fp32 stores + bias.
#pragma unroll
      for (int mt = 0; mt < 8; ++mt) {
#pragma unroll
        for (int r = 0; r < 4; ++r) {
          const int t = bm * 256 + wm * 128 + mt * 16 + lq * 4 + r;
          float* op = Out + (size_t)t * CDIM + bnv * 256 + wn * 64 + lr;
#pragma unroll
          for (int nt = 0; nt < 4; ++nt)
            op[nt * 16] = acc[mt][nt][r] + bias[bnv * 256 + wn * 64 + nt * 16 + lr];
        }
      }
    }
  };

  // prologue: buf0 tile0 fully; buf1 {Ah0,Bh1,Ah1} (B1h0@64 staged at ph1, j=0)
  STA(A0, AgC, 0, 0);
  STB(B0, BgC, 0, 0);
  STB(B0, BgC, 0, 1);
  STA(A0, AgC, 0, 1);
  STA(A1, AgC, 64, 0);
  STB(B1, BgC, 64, 1);
  STA(A1, AgC, 64, 1);
  VMW6();            // all of buf0 (first 8 loads) landed
  BARR();

#pragma unroll 1
  for (int j = 0; j < 8 * NTILES - 1; ++j) {
    const int kl = (j & 7) << 7;
    const bf16* sA = AgC;
    const bf16* sB = BgC;
    int k1 = kl + 128, k2 = kl + 192;
    if (k1 == 1024) { sA = AgX; sB = BgX; k1 = 0; k2 = 64; }  // tile wrap
    FULL_ITER_BODY();
    if ((j & 7) == 7) {
      // tile finished; next tile's first K-tiles already staged/in-flight.
      epilogue(bn, swapped);
#pragma unroll
      for (int mi = 0; mi < 8; ++mi)
#pragma unroll
        for (int ni = 0; ni < 4; ++ni) acc[mi][ni] = (f32x4){0.f, 0.f, 0.f, 0.f};
      bn += 1;
      swapped = (EPI == 0) && (bn < 4);
      AgC = AgX; BgC = BgX;
      const bool swX = (EPI == 0) && ((bn + 1) < 4);   // may index one-past; never staged
      const bf16* WgX = W + (size_t)((bn + 1) * 256) * K;
      AgX = swX ? WgX : Xg;
      BgX = swX ? Xg : WgX;
    }
  }
  FINAL_ITER_BODY();
  epilogue(bn, swapped);
}

// ---------------------------------------------------------------------------
// kv partials via MFMA.  Inputs K^T,V^T [bh][d][n] (n contiguous).
// Same T2 involution: LDS[row][c] = global[row][c ^ ((row&7)*8)].
// ---------------------------------------------------------------------------
__global__ __launch_bounds__(256) void kv_mfma(const bf16* __restrict__ KT,
                                               const bf16* __restrict__ VT,
                                               float* __restrict__ KVp,
                                               float* __restrict__ KSp) {
  __shared__ bf16 kt[64 * 64];
  __shared__ bf16 vt[64 * 64];
  const int tid = threadIdx.x;
  const int w = tid >> 6, lane = tid & 63;
  const int wm = w >> 1, wn = w & 1;
  const int lr = lane & 15, lq = lane >> 4;
  const int swz = (lr & 7) * 8;                            // read-side XOR
  const int csz = (((lane & 7) ^ (lane >> 3)) * 8);        // src-side pre-swizzle
  const int sp = blockIdx.x, bh = blockIdx.y;
  const bf16* kg0 = KT + (size_t)bh * 64 * SEQ + sp * 512;
  const bf16* vg0 = VT + (size_t)bh * 64 * SEQ + sp * 512;

  f32x4 acc[2][2] = {};
  f32x4 kacc0 = {}, kacc1 = {};
  short8 ones;
#pragma unroll
  for (int j = 0; j < 8; ++j) ((unsigned short*)&ones)[j] = 0x3F80;  // bf16 1.0

  for (int nc = 0; nc < 8; ++nc) {
    __syncthreads();
#pragma unroll
    for (int i = 0; i < 2; ++i) {
      const int row = w * 16 + i * 8 + (lane >> 3);
      async_load16(kg0 + (size_t)row * SEQ + nc * 64 + csz, kt + (w * 16 + i * 8) * 64);
      async_load16(vg0 + (size_t)row * SEQ + nc * 64 + csz, vt + (w * 16 + i * 8) * 64);
    }
    __syncthreads();

#pragma unroll
    for (int ks = 0; ks < 2; ++ks) {
      short8 a0 = *(const short8*)&kt[(wm * 32 +      lr) * 64 + ((ks * 32 + lq * 8) ^ swz)];
      short8 a1 = *(const short8*)&kt[(wm * 32 + 16 + lr) * 64 + ((ks * 32 + lq * 8) ^ swz)];
      short8 b0 = *(const short8*)&vt[(wn * 32 +      lr) * 64 + ((ks * 32 + lq * 8) ^ swz)];
      short8 b1 = *(const short8*)&vt[(wn * 32 + 16 + lr) * 64 + ((ks * 32 + lq * 8) ^ swz)];
      acc[0][0] = __builtin_amdgcn_mfma_f32_16x16x32_bf16(a0, b0, acc[0][0], 0, 0, 0);
      acc[0][1] = __builtin_amdgcn_mfma_f32_16x16x32_bf16(a0, b1, acc[0][1], 0, 0, 0);
      acc[1][0] = __builtin_amdgcn_mfma_f32_16x16x32_bf16(a1, b0, acc[1][0], 0, 0, 0);
      acc[1][1] = __builtin_amdgcn_mfma_f32_16x16x32_bf16(a1, b1, acc[1][1], 0, 0, 0);
      kacc0 = __builtin_amdgcn_mfma_f32_16x16x32_bf16(a0, ones, kacc0, 0, 0, 0);
      kacc1 = __builtin_amdgcn_mfma_f32_16x16x32_bf16(a1, ones, kacc1, 0, 0, 0);
    }
  }

  float* outp = KVp + ((size_t)(sp * 64 + bh)) * 4096;
#pragma unroll
  for (int mt = 0; mt < 2; ++mt)
#pragma unroll
    for (int nt = 0; nt < 2; ++nt) {
      const int e  = wn * 32 + nt * 16 + lr;
      const int d0 = wm * 32 + mt * 16 + lq * 4;
      *(float4*)&outp[e * 64 + d0] = *(float4*)&acc[mt][nt];
    }
  if (wn == 0 && lr == 0) {
    float* ksp = KSp + (size_t)(sp * 64 + bh) * 64 + wm * 32;
#pragma unroll
    for (int r = 0; r < 4; ++r) {
      ksp[lq * 4 + r]      = kacc0[r];
      ksp[16 + lq * 4 + r] = kacc1[r];
    }
  }
}

// ---------------------------------------------------------------------------
// reduce partials. grid 256 = (bh 64) x (quarter 4).
// ---------------------------------------------------------------------------
__global__ __launch_bounds__(256) void kv_reduce(const float* __restrict__ KVp,
                                                 const float* __restrict__ KSp,
                                                 bf16* __restrict__ KVT,
                                                 float* __restrict__ KS) {
  const int bh = blockIdx.x >> 2, q = blockIdx.x & 3, t = threadIdx.x;
#pragma unroll
  for (int i = 0; i < 4; ++i) {
    const int idx = (q * 4 + i) * 256 + t;
    float s = 0.0f;
#pragma unroll
    for (int sp = 0; sp < 8; ++sp) s += KVp[((size_t)(sp * 64 + bh)) * 4096 + idx];
    const bf16 hi = __float2bfloat16(s);
    const float lo = s - __bfloat162float(hi);
    const int e = idx >> 6, d = idx & 63;
    KVT[(size_t)bh * 8192 + e * 128 + d]      = hi;
    KVT[(size_t)bh * 8192 + e * 128 + 64 + d] = __float2bfloat16(lo);
  }
  if (q == 0 && t < 64) {
    float s = 0.0f;
#pragma unroll
    for (int sp = 0; sp < 8; ++sp) s += KSp[(sp * 64 + bh) * 64 + t];
    KS[bh * 64 + t] = s;
  }
}

// ---------------------------------------------------------------------------
// num = q @ kv. qs [128][64] and kvs [64][128] both carry the T2 involution
// LDS[row][c] = global[row][c ^ ((row&7)*8)] (chunk-granular, 8-elem chunks).
// ---------------------------------------------------------------------------
__global__ __launch_bounds__(256) void num_mfma(const bf16* __restrict__ Qb,
                                                const bf16* __restrict__ KVT,
                                                const float* __restrict__ KS,
                                                bf16* __restrict__ Attn) {
  __shared__ bf16 qs[128 * 64];
  __shared__ bf16 kvs[64 * 128];
  __shared__ bf16 Cs[128 * 72];
  __shared__ float ksl[64];
  __shared__ float dred[256];
  __shared__ float den[128];
  const int tid = threadIdx.x;
  const int w = tid >> 6, lane = tid & 63;
  const int wm = w >> 1, wn = w & 1;
  const int lr = lane & 15, lq = lane >> 4;
  const int swz = (lr & 7) * 8;
  const int bh = blockIdx.y, n00 = blockIdx.x * 128;
  const int b = bh >> 4, h = bh & 15;

  const bf16* qg  = Qb  + ((size_t)bh * SEQ + n00) * 64;
  const bf16* kvg = KVT + (size_t)bh * 8192;
  const int qcs = (((lane & 7) ^ (lane >> 3)) * 8);
#pragma unroll
  for (int i = 0; i < 4; ++i) {
    const int row = w * 32 + i * 8 + (lane >> 3);
    async_load16(qg + (size_t)row * 64 + qcs, qs + (w * 32 + i * 8) * 64);
  }
#pragma unroll
  for (int i = 0; i < 4; ++i) {
    const int row = w * 16 + i * 4 + (lane >> 4);
    const int scol = (((lane & 15) * 8) ^ ((row & 7) * 8));
    async_load16(kvg + (size_t)row * 128 + scol, kvs + (w * 16 + i * 4) * 128);
  }
  if (tid < 64) ksl[tid] = KS[bh * 64 + tid];
  __syncthreads();

  {
    const int n = tid >> 1, half = tid & 1;
    const int nsw = (n & 7) * 8;
    float s = 0.0f;
#pragma unroll
    for (int v8 = 0; v8 < 4; ++v8) {
      short8 qq = *(const short8*)&qs[n * 64 + ((half * 32 + v8 * 8) ^ nsw)];
#pragma unroll
      for (int j = 0; j < 8; ++j)
        s += __bfloat162float(((const bf16*)&qq)[j]) * ksl[half * 32 + v8 * 8 + j];
    }
    dred[tid] = s;
  }

  short8 afr[4][2], bfr2[2][4];
#pragma unroll
  for (int mt = 0; mt < 4; ++mt)
#pragma unroll
    for (int kh = 0; kh < 2; ++kh)
      afr[mt][kh] = *(const short8*)&qs[(wm * 64 + mt * 16 + lr) * 64 + ((kh * 32 + lq * 8) ^ swz)];
#pragma unroll
  for (int nt = 0; nt < 2; ++nt)
#pragma unroll
    for (int ks = 0; ks < 4; ++ks)
      bfr2[nt][ks] = *(const short8*)&kvs[(wn * 32 + nt * 16 + lr) * 128 + ((ks * 32 + lq * 8) ^ swz)];

  f32x4 acc[4][2] = {};
#pragma unroll
  for (int ks = 0; ks < 4; ++ks)
#pragma unroll
    for (int mt = 0; mt < 4; ++mt)
#pragma unroll
      for (int nt = 0; nt < 2; ++nt)
        acc[mt][nt] = __builtin_amdgcn_mfma_f32_16x16x32_bf16(afr[mt][ks & 1], bfr2[nt][ks],
                                                              acc[mt][nt], 0, 0, 0);
  __syncthreads();
  if (tid < 128) den[tid] = dred[tid * 2] + dred[tid * 2 + 1] + 1e-8f;
  __syncthreads();

#pragma unroll
  for (int mt = 0; mt < 4; ++mt) {
#pragma unroll
    for (int r = 0; r < 4; ++r) {
      const int nl = wm * 64 + mt * 16 + lq * 4 + r;
      const float inv = 1.0f / den[nl];
#pragma unroll
      for (int nt = 0; nt < 2; ++nt) {
        const int e = wn * 32 + nt * 16 + lr;
        Cs[nl * 72 + e] = __float2bfloat16(acc[mt][nt][r] * inv);
      }
    }
  }
  __syncthreads();
#pragma unroll
  for (int it = 0; it < 4; ++it) {
    const int nl = it * 32 + (tid >> 3);
    const int ch = tid & 7;
    short8 val = *(const short8*)&Cs[nl * 72 + ch * 8];
    *(short8*)(Attn + ((size_t)(b * SEQ + n00 + nl)) * CDIM + h * 64 + ch * 8) = val;
  }
}

// ---------------------------------------------------------------------------
extern "C" void kernel_launch(void* const* d_in, const int* in_sizes, int n_in,
                              void* d_out, int out_size, void* d_ws, size_t ws_size,
                              hipStream_t stream) {
  const float* x      = (const float*)d_in[0];
  const float* w_qkv  = (const float*)d_in[1];
  const float* w_proj = (const float*)d_in[2];
  const float* b_proj = (const float*)d_in[3];
  float* out = (float*)d_out;
  char* ws = (char*)d_ws;

  bf16*  xb     = (bf16*)(ws + 0);
  bf16*  wqkvb  = (bf16*)(ws + 33554432);
  bf16*  wprojb = (bf16*)(ws + 39845888);
  bf16*  qb     = (bf16*)(ws + 41943040);
  bf16*  ktb    = (bf16*)(ws + 75497472);
  bf16*  vtb    = (bf16*)(ws + 109051904);
  float* kvp    = (float*)(ws + 0);
  float* ksp    = (float*)(ws + 8388608);
  bf16*  kvt    = (bf16*)(ws + 142606336);
  float* ksum   = (float*)(ws + 143654912);
  bf16*  attn   = (bf16*)(ws + 0);

  convert3_kernel<<<20480, 256, 0, stream>>>(x, w_qkv, w_proj, xb, wqkvb, wprojb);

  gemm256<0, 3><<<256, 512, 0, stream>>>(xb, wqkvb, nullptr, qb, ktb, vtb, nullptr, 1024);
  kv_mfma<<<dim3(8, 64), 256, 0, stream>>>(ktb, vtb, kvp, ksp);
  kv_reduce<<<256, 256, 0, stream>>>(kvp, ksp, kvt, ksum);
  num_mfma<<<dim3(32, 64), 256, 0, stream>>>(qb, kvt, ksum, attn);
  gemm256<1, 1><<<256, 512, 0, stream>>>(attn, wprojb, b_proj, nullptr, nullptr, nullptr, out, 1024);
}